// Round 3
// baseline (1582.288 us; speedup 1.0000x reference)
//
#include <hip/hip_runtime.h>

// Problem constants (match reference)
#define N_NODES    1000000
#define N_EDGES    16000000
#define D          30
#define WINDOW     5
#define DEG_THRESH 10

// ---- partitioned-histogram edge pass ----
#define P_PARTS        32
#define B_SLICES       16
#define NODES_PER_PART (N_NODES / P_PARTS)     // 31250
#define HIST_WORDS     (NODES_PER_PART / 2)    // 15625 u32 (2 nodes/word)
#define EDGES_PER_SLICE (N_EDGES / B_SLICES)   // 1,000,000
#define GROUPS_PER_SLICE (EDGES_PER_SLICE / 4) // 250,000 int4-groups
#define WS_NEEDED ((size_t)P_PARTS * B_SLICES * HIST_WORDS * 4)  // 32 MB

#define NPB 64   // nodes per out_pass block

// ---------------------------------------------------------------------------
// Edge pass, NO global atomics: block (p,b) scans edge-slice b and builds an
// LDS histogram for node range p. Per node u16: cnt_type0_nbrs | cnt_type1<<8.
// Edge stream (128 MB) is L3-resident, so the P x re-read is cheap.
// ---------------------------------------------------------------------------
__global__ __launch_bounds__(512) void edge_hist(
    const int* __restrict__ edge_index,   // [2, N_EDGES] int32
    const int* __restrict__ atom_types,   // [N_NODES] int32 in {0,1}
    unsigned*  __restrict__ partial)      // [P*B][HIST_WORDS]
{
    __shared__ unsigned hist[HIST_WORDS];

    const int p   = blockIdx.x & (P_PARTS - 1);
    const int b   = blockIdx.x >> 5;
    const int lo  = p * NODES_PER_PART;
    const int tid = threadIdx.x;

    for (int i = tid; i < HIST_WORDS; i += 512) hist[i] = 0u;
    __syncthreads();

    const int gbase = b * GROUPS_PER_SLICE;
    for (int g = tid; g < GROUPS_PER_SLICE; g += 512) {
        const int e0 = (gbase + g) * 4;
        const int4 s4 = *reinterpret_cast<const int4*>(edge_index + e0);
        const int4 d4 = *reinterpret_cast<const int4*>(edge_index + N_EDGES + e0);
        const int ss[4] = {s4.x, s4.y, s4.z, s4.w};
        const int dd[4] = {d4.x, d4.y, d4.z, d4.w};
#pragma unroll
        for (int k = 0; k < 4; ++k) {
            const int s = ss[k], d = dd[k];
            const unsigned us = (unsigned)(s - lo);
            const unsigned ud = (unsigned)(d - lo);
            if (us < NODES_PER_PART) {
                const int tn = atom_types[d];           // neighbor's type
                const unsigned add = (1u << (8 * tn)) << (16 * (us & 1));
                atomicAdd(&hist[us >> 1], add);         // LDS atomic
            }
            if (ud < NODES_PER_PART) {
                const int tn = atom_types[s];
                const unsigned add = (1u << (8 * tn)) << (16 * (ud & 1));
                atomicAdd(&hist[ud >> 1], add);
            }
        }
    }
    __syncthreads();

    unsigned* outp = partial + (size_t)blockIdx.x * HIST_WORDS;
    for (int i = tid; i < HIST_WORDS; i += 512) outp[i] = hist[i];  // plain writes
}

// ---------------------------------------------------------------------------
// Output pass (partitioned source): reduce 16 partials -> crit -> window,
// then one dot-product per thread (320 dots/block), LDS padded to stride 36.
// ---------------------------------------------------------------------------
__global__ __launch_bounds__(256) void out_pass_part(
    const float* __restrict__ x,          // [N_NODES, D]
    const float* __restrict__ W,          // [D, D]
    const unsigned short* __restrict__ partial,  // u16 view of edge_hist output
    const int*   __restrict__ atom_types,
    float* __restrict__ out)              // [N_NODES, D]
{
    __shared__ float sx[NPB][36];         // x tile, padded
    __shared__ float sWt[D][36];          // W transposed: sWt[col][k]
    __shared__ int   sstart[NPB];

    const int tid   = threadIdx.x;
    const long base = (long)blockIdx.x * NPB;

    for (int i = tid; i < D * D; i += 256) {
        const int k = i / D, c = i - k * D;
        sWt[c][k] = W[i];
    }
    const float* xb = x + base * D;
    for (int i = tid; i < NPB * D; i += 256) {
        const int nd = i / D, c = i - nd * D;
        sx[nd][c] = xb[i];
    }
    if (tid < NPB) {
        const int n  = (int)(base + tid);
        const int p  = n / NODES_PER_PART;
        const int ii = n - p * NODES_PER_PART;
        const unsigned short* pp = partial + (size_t)p * NODES_PER_PART + ii;
        unsigned c0 = 0, c1 = 0;
#pragma unroll
        for (int b = 0; b < B_SLICES; ++b) {
            const unsigned v = pp[(size_t)(b * P_PARTS) * NODES_PER_PART];
            c0 += v & 0xFFu;
            c1 += v >> 8;
        }
        const int t = atom_types[n];
        const unsigned cnt    = c0 + c1;
        const unsigned same_c = t ? c1 : c0;
        const unsigned diff_c = t ? c0 : c1;
        const int mix  = diff_c ? 0 : (same_c ? t + 1 : 0);
        const int crit = (cnt > DEG_THRESH ? 3 : 0) + mix;
        sstart[tid] = crit * WINDOW;
    }
    __syncthreads();

    float* ob = out + base * D;
    // Zero-fill only out-of-window elements (coalesced-with-holes; no address
    // is written twice, so no intra-block store race).
    for (int i = tid; i < NPB * D; i += 256) {
        const int nd = i / D, c = i - nd * D;
        if ((unsigned)(c - sstart[nd]) >= WINDOW) ob[i] = 0.0f;
    }

    const float scale = 0.18257418583505536f;   // 1/sqrt(30)
    for (int d0 = tid; d0 < NPB * WINDOW; d0 += 256) {
        const int nd  = d0 / WINDOW;
        const int cc  = d0 - nd * WINDOW;
        const int col = sstart[nd] + cc;
        const float* xr = sx[nd];
        const float* wr = sWt[col];
        float acc = 0.0f;
#pragma unroll
        for (int k = 0; k < 28; k += 4)
            acc += xr[k]*wr[k] + xr[k+1]*wr[k+1] + xr[k+2]*wr[k+2] + xr[k+3]*wr[k+3];
        acc += xr[28]*wr[28] + xr[29]*wr[29];
        ob[nd * D + col] = acc * scale;
    }
}

// ===========================================================================
// Fallback path (round-2 atomic version) in case ws_size < 32 MB.
// ===========================================================================
#define SAME_INC (1u << 12)
#define DIFF_INC (1u << 22)
#define EDGES_PER_THREAD 4

__global__ __launch_bounds__(256) void edge_pass_atomic(
    const int* __restrict__ edge_index,
    const int* __restrict__ atom_types,
    unsigned*  __restrict__ agg)
{
    const int t  = blockIdx.x * blockDim.x + threadIdx.x;
    const int e0 = t * EDGES_PER_THREAD;
    if (e0 >= N_EDGES) return;
    const int4 s4 = *reinterpret_cast<const int4*>(edge_index + e0);
    const int4 d4 = *reinterpret_cast<const int4*>(edge_index + N_EDGES + e0);
    const int ss[4] = {s4.x, s4.y, s4.z, s4.w};
    const int dd[4] = {d4.x, d4.y, d4.z, d4.w};
#pragma unroll
    for (int k = 0; k < 4; ++k) {
        const int s = ss[k], d = dd[k];
        const int ts = atom_types[s], td = atom_types[d];
        const unsigned add = 1u + ((ts == td) ? SAME_INC : DIFF_INC);
        atomicAdd(agg + s, add);
        atomicAdd(agg + d, add);
    }
}

__global__ __launch_bounds__(256) void out_pass_agg(
    const float* __restrict__ x, const float* __restrict__ W,
    const unsigned* __restrict__ agg, const int* __restrict__ atom_types,
    float* __restrict__ out)
{
    __shared__ float sx[NPB * D];
    __shared__ float sW[D * D];
    __shared__ int   sstart[NPB];
    const int tid   = threadIdx.x;
    const long base = (long)blockIdx.x * NPB;
    for (int i = tid; i < D * D; i += 256) sW[i] = W[i];
    const float* xb = x + base * D;
    for (int i = tid; i < NPB * D; i += 256) sx[i] = xb[i];
    if (tid < NPB) {
        const long n = base + tid;
        const unsigned a = agg[n];
        const int cnt = a & 0xFFFu;
        const int same_cnt = (a >> 12) & 0x3FFu;
        const int diff_cnt = a >> 22;
        const int mix  = diff_cnt ? 0 : (same_cnt ? atom_types[n] + 1 : 0);
        const int crit = (cnt > DEG_THRESH ? 3 : 0) + mix;
        sstart[tid] = crit * WINDOW;
    }
    __syncthreads();
    const float scale = 0.18257418583505536f;
    float* ob = out + base * D;
    for (int i = tid; i < NPB * D; i += 256) {
        const int nd = i / D, c = i - nd * D;
        float v = 0.0f;
        if ((unsigned)(c - sstart[nd]) < WINDOW) {
            const float* xr = &sx[nd * D];
            float acc = 0.0f;
#pragma unroll
            for (int k = 0; k < D; ++k) acc += xr[k] * sW[k * D + c];
            v = acc * scale;
        }
        ob[i] = v;
    }
}

// ---------------------------------------------------------------------------
extern "C" void kernel_launch(void* const* d_in, const int* in_sizes, int n_in,
                              void* d_out, int out_size, void* d_ws, size_t ws_size,
                              hipStream_t stream)
{
    const float* x          = (const float*)d_in[0];
    const float* W          = (const float*)d_in[1];
    const int*   edge_index = (const int*)d_in[2];
    const int*   atom_types = (const int*)d_in[3];
    float* out = (float*)d_out;

    const int nblocks = N_NODES / NPB;   // 15625

    if (ws_size >= WS_NEEDED) {
        unsigned* partial = (unsigned*)d_ws;   // 32 MB, fully written each call
        edge_hist<<<P_PARTS * B_SLICES, 512, 0, stream>>>(edge_index, atom_types,
                                                          partial);
        out_pass_part<<<nblocks, 256, 0, stream>>>(x, W,
                                                   (const unsigned short*)partial,
                                                   atom_types, out);
    } else {
        unsigned* agg = (unsigned*)d_ws;       // 4 MB
        hipMemsetAsync(agg, 0x00, N_NODES * sizeof(unsigned), stream);
        edge_pass_atomic<<<(N_EDGES / EDGES_PER_THREAD) / 256, 256, 0, stream>>>(
            edge_index, atom_types, agg);
        out_pass_agg<<<nblocks, 256, 0, stream>>>(x, W, agg, atom_types, out);
    }
}

// Round 4
// 483.024 us; speedup vs baseline: 3.2758x; 3.2758x over previous
//
#include <hip/hip_runtime.h>

// Problem constants (match reference)
#define N_NODES    1000000
#define N_EDGES    16000000
#define D          30
#define WINDOW     5
#define DEG_THRESH 10

// ---- binning params ----
#define P_PARTS    31                 // partitions of 32768 nodes (1e6 >> 15 = 30)
#define PART_BITS  15
#define PART_SIZE  32768
#define CAP        1081344            // records/bucket: mean 1.0486M + 32k (~32 sigma)
#define BIN_BLOCKS 512
#define BIN_THREADS 512
#define BIN_ITERS  16                 // 512*512*16 = 4,194,304 groups >= 4M
#define N_GROUPS   (N_EDGES / 4)      // 4,000,000 int4-groups
#define BUF_CAP    512                // LDS staging entries per bucket

// ---- phase 2 ----
#define SLICES     8
#define HIST_WORDS 16384              // 32768 nodes, u32 per 2 nodes (c0:u8|c1:u8 each)

// ---- ws layout (bytes); total ~17.6 MB (round 3 proved ws >= 32 MB) ----
#define WS_BM_OFF      0              // u32[32768] type bitmask (131072 B)
#define WS_CUR_OFF     131072         // u32[64] bucket cursors
#define WS_STARTS_OFF  131328         // u8[1,000,000] per-node window start
#define WS_PART_OFF    1310720        // u32[248 * 16384] slice partials (15.5 MiB)
#define WS_NEEDED      (WS_PART_OFF + (size_t)P_PARTS * SLICES * HIST_WORDS * 4)
#define OUT_BYTES_NEEDED ((size_t)P_PARTS * CAP * 2)   // 67 MB of d_out as bucket scratch

// ---------------------------------------------------------------------------
// Phase 0: pack atom_types into a 1-bit-per-node bitmask; zero bucket cursors.
// ---------------------------------------------------------------------------
__global__ __launch_bounds__(256) void pack_types(
    const int* __restrict__ types,
    unsigned*  __restrict__ bm,
    unsigned*  __restrict__ cursors)
{
    const int g = blockIdx.x * 256 + threadIdx.x;
    const int v = (g < N_NODES) ? types[g] : 0;
    const unsigned long long m = __ballot(v);
    if ((threadIdx.x & 31) == 0 && g < N_NODES)
        bm[g >> 5] = (unsigned)(m >> (threadIdx.x & 32));
    if (blockIdx.x == 0 && threadIdx.x < 64) cursors[threadIdx.x] = 0u;
}

// ---------------------------------------------------------------------------
// Phase 1: single pass over edges -> binned u16 records (local_id<<1 | ntype).
// LDS-staged per-partition buckets, flushed coalesced each iteration with ONE
// global cursor atomic per non-empty bucket. No per-record global atomics.
// ---------------------------------------------------------------------------
__global__ __launch_bounds__(512) void bin_edges(
    const int*      __restrict__ edge_index,   // [2, N_EDGES] int32
    const unsigned* __restrict__ bm,           // type bitmask
    unsigned short* __restrict__ buckets,      // [P_PARTS][CAP] (in d_out scratch)
    unsigned*       __restrict__ cursors)      // [P_PARTS]
{
    __shared__ unsigned short buf[P_PARTS][BUF_CAP];   // 31,744 B
    __shared__ unsigned cnt[P_PARTS];
    __shared__ unsigned basev[P_PARTS];
    __shared__ unsigned ccnt[P_PARTS];

    const int tid = threadIdx.x;
    if (tid < P_PARTS) cnt[tid] = 0u;
    __syncthreads();

    for (int it = 0; it < BIN_ITERS; ++it) {
        const int g = (blockIdx.x * BIN_ITERS + it) * BIN_THREADS + tid;
        if (g < N_GROUPS) {
            const int e0 = g * 4;
            const int4 s4 = *reinterpret_cast<const int4*>(edge_index + e0);
            const int4 d4 = *reinterpret_cast<const int4*>(edge_index + N_EDGES + e0);
            const int ss[4] = {s4.x, s4.y, s4.z, s4.w};
            const int dd[4] = {d4.x, d4.y, d4.z, d4.w};
#pragma unroll
            for (int k = 0; k < 4; ++k) {
                const int s = ss[k], d = dd[k];
                const unsigned ts = (bm[(unsigned)s >> 5] >> (s & 31)) & 1u;
                const unsigned td = (bm[(unsigned)d >> 5] >> (d & 31)) & 1u;
                {   // record for endpoint s carries d's type
                    const int b = s >> PART_BITS;
                    const unsigned short rec =
                        (unsigned short)(((s & (PART_SIZE - 1)) << 1) | td);
                    const unsigned pos = atomicAdd(&cnt[b], 1u);
                    if (pos < BUF_CAP) buf[b][pos] = rec;
                    else {  // statistically ~never: direct spill
                        const unsigned gp = atomicAdd(&cursors[b], 1u);
                        if (gp < CAP) buckets[(size_t)b * CAP + gp] = rec;
                    }
                }
                {   // record for endpoint d carries s's type
                    const int b = d >> PART_BITS;
                    const unsigned short rec =
                        (unsigned short)(((d & (PART_SIZE - 1)) << 1) | ts);
                    const unsigned pos = atomicAdd(&cnt[b], 1u);
                    if (pos < BUF_CAP) buf[b][pos] = rec;
                    else {
                        const unsigned gp = atomicAdd(&cursors[b], 1u);
                        if (gp < CAP) buckets[(size_t)b * CAP + gp] = rec;
                    }
                }
            }
        }
        __syncthreads();
        if (tid < P_PARTS) {
            unsigned c = cnt[tid]; if (c > BUF_CAP) c = BUF_CAP;
            unsigned bse = 0u;
            if (c) {
                bse = atomicAdd(&cursors[tid], c);
                if (bse > CAP) bse = CAP;
                if (bse + c > CAP) c = CAP - bse;   // memory-safety clamp
            }
            ccnt[tid] = c; basev[tid] = bse; cnt[tid] = 0u;
        }
        __syncthreads();
        // coalesced flush: wave w copies buckets 4w..4w+3
        const int w = tid >> 6, lane = tid & 63;
#pragma unroll
        for (int j = 0; j < 4; ++j) {
            const int b = w * 4 + j;
            if (b < P_PARTS) {
                const unsigned c = ccnt[b];
                unsigned short* dst = buckets + (size_t)b * CAP + basev[b];
                for (unsigned e = lane; e < c; e += 64) dst[e] = buf[b][e];
            }
        }
        __syncthreads();
    }
}

// ---------------------------------------------------------------------------
// Phase 2: per (partition, slice) block builds a 64 KB LDS histogram
// (c0:u8 | c1:u8 per node, 2 nodes per u32) from its record slice.
// ---------------------------------------------------------------------------
__global__ __launch_bounds__(512) void hist_pass(
    const unsigned short* __restrict__ buckets,
    const unsigned*       __restrict__ cursors,
    unsigned*             __restrict__ partials)   // [P*SLICES][HIST_WORDS]
{
    __shared__ unsigned hist[HIST_WORDS];          // exactly 64 KiB
    const int p = blockIdx.x >> 3, s = blockIdx.x & 7;
    const int tid = threadIdx.x;
    for (int i = tid; i < HIST_WORDS; i += 512) hist[i] = 0u;
    __syncthreads();

    unsigned count = cursors[p]; if (count > CAP) count = CAP;
    const unsigned short* bk = buckets + (size_t)p * CAP;
    const unsigned n4 = (count + 3u) >> 2;
    for (unsigned j = (unsigned)(s * 512 + tid); j < n4; j += SLICES * 512) {
        const unsigned i0 = j * 4u;
        if (i0 + 4u <= count) {
            const ushort4 r4 = *reinterpret_cast<const ushort4*>(bk + i0);
            const unsigned short rr[4] = {r4.x, r4.y, r4.z, r4.w};
#pragma unroll
            for (int k = 0; k < 4; ++k) {
                const unsigned rec = rr[k];
                const unsigned local = rec >> 1, t = rec & 1u;
                atomicAdd(&hist[local >> 1], (1u << (8u * t)) << (16u * (local & 1u)));
            }
        } else {
            for (unsigned i = i0; i < count; ++i) {
                const unsigned rec = bk[i];
                const unsigned local = rec >> 1, t = rec & 1u;
                atomicAdd(&hist[local >> 1], (1u << (8u * t)) << (16u * (local & 1u)));
            }
        }
    }
    __syncthreads();
    unsigned* op = partials + (size_t)blockIdx.x * HIST_WORDS;
    for (int i = tid; i < HIST_WORDS; i += 512) op[i] = hist[i];
}

// ---------------------------------------------------------------------------
// Phase 3: SWAR-reduce 8 slice partials (byte fields, totals < 256 so adds
// never carry), decode crit, emit per-node window start (u8).
// ---------------------------------------------------------------------------
__global__ __launch_bounds__(256) void reduce_crit(
    const unsigned* __restrict__ partials,
    const unsigned* __restrict__ bm,
    unsigned short* __restrict__ starts16)    // 2 starts per u16
{
    const unsigned Wd = blockIdx.x * 256 + threadIdx.x;   // word = 2 nodes
    if (Wd >= N_NODES / 2) return;
    const unsigned p = Wd >> 14, widx = Wd & 16383u;
    const unsigned* pp = partials + (size_t)(p * SLICES) * HIST_WORDS + widx;
    unsigned sum = 0u;
#pragma unroll
    for (int s = 0; s < SLICES; ++s) sum += pp[(size_t)s * HIST_WORDS];
    const unsigned bmw = bm[Wd >> 4];
    unsigned st[2];
#pragma unroll
    for (int h = 0; h < 2; ++h) {
        const unsigned c0 = (sum >> (16 * h)) & 0xFFu;
        const unsigned c1 = (sum >> (16 * h + 8)) & 0xFFu;
        const unsigned t  = (bmw >> ((Wd & 15u) * 2u + (unsigned)h)) & 1u;
        const unsigned cnt    = c0 + c1;
        const unsigned same_c = t ? c1 : c0;
        const unsigned diff_c = t ? c0 : c1;
        const int mix  = diff_c ? 0 : (same_c ? (int)t + 1 : 0);
        const int crit = (cnt > DEG_THRESH ? 3 : 0) + mix;
        st[h] = (unsigned)(crit * WINDOW);
    }
    starts16[Wd] = (unsigned short)(st[0] | (st[1] << 8));
}

// ---------------------------------------------------------------------------
// Phase 4: output. x row in registers, 5 dots vs LDS W, row assembled in LDS
// (sx reused), fully coalesced global in/out.
// ---------------------------------------------------------------------------
#define ONPB 256
__global__ __launch_bounds__(256) void out_pass(
    const float* __restrict__ x, const float* __restrict__ Wm,
    const unsigned char* __restrict__ starts, float* __restrict__ out)
{
    __shared__ float sx[ONPB * 31];     // padded rows (stride 31)
    __shared__ float sW[D * D];
    __shared__ unsigned char sst[ONPB];
    const int tid   = threadIdx.x;
    const long base = (long)blockIdx.x * ONPB;
    const long tot  = (long)N_NODES * D;

    for (int i = tid; i < D * D; i += 256) sW[i] = Wm[i];
    for (int i = tid; i < ONPB * D; i += 256) {
        const int n = i / D, c = i - n * D;
        const long gi = base * D + i;
        sx[n * 31 + c] = (gi < tot) ? x[gi] : 0.0f;
    }
    {
        const long n = base + tid;
        sst[tid] = (n < N_NODES) ? starts[n] : 0;
    }
    __syncthreads();

    float xr[D];
#pragma unroll
    for (int k = 0; k < D; ++k) xr[k] = sx[tid * 31 + k];
    const int start = sst[tid];
    float acc[WINDOW];
#pragma unroll
    for (int cc = 0; cc < WINDOW; ++cc) {
        const int col = start + cc;
        float a = 0.0f;
#pragma unroll
        for (int k = 0; k < D; ++k) a += xr[k] * sW[k * D + col];
        acc[cc] = a * 0.18257418583505536f;   // 1/sqrt(30)
    }
    __syncthreads();                          // everyone done reading sx
#pragma unroll
    for (int k = 0; k < D; ++k) sx[tid * 31 + k] = 0.0f;
#pragma unroll
    for (int cc = 0; cc < WINDOW; ++cc) sx[tid * 31 + start + cc] = acc[cc];
    __syncthreads();
    for (int i = tid; i < ONPB * D; i += 256) {
        const int n = i / D, c = i - n * D;
        const long gi = base * D + i;
        if (gi < tot) out[gi] = sx[n * 31 + c];
    }
}

// ===========================================================================
// Fallback (round-2 atomic path) if buffers are unexpectedly small.
// ===========================================================================
#define SAME_INC (1u << 12)
#define DIFF_INC (1u << 22)

__global__ __launch_bounds__(256) void edge_pass_atomic(
    const int* __restrict__ edge_index, const int* __restrict__ atom_types,
    unsigned* __restrict__ agg)
{
    const int t  = blockIdx.x * blockDim.x + threadIdx.x;
    const int e0 = t * 4;
    if (e0 >= N_EDGES) return;
    const int4 s4 = *reinterpret_cast<const int4*>(edge_index + e0);
    const int4 d4 = *reinterpret_cast<const int4*>(edge_index + N_EDGES + e0);
    const int ss[4] = {s4.x, s4.y, s4.z, s4.w};
    const int dd[4] = {d4.x, d4.y, d4.z, d4.w};
#pragma unroll
    for (int k = 0; k < 4; ++k) {
        const int s = ss[k], d = dd[k];
        const unsigned add = 1u + ((atom_types[s] == atom_types[d]) ? SAME_INC : DIFF_INC);
        atomicAdd(agg + s, add);
        atomicAdd(agg + d, add);
    }
}

__global__ __launch_bounds__(256) void out_pass_agg(
    const float* __restrict__ x, const float* __restrict__ Wm,
    const unsigned* __restrict__ agg, const int* __restrict__ atom_types,
    float* __restrict__ out)
{
    __shared__ float sx[64 * D];
    __shared__ float sW[D * D];
    __shared__ int   sstart[64];
    const int tid   = threadIdx.x;
    const long base = (long)blockIdx.x * 64;
    for (int i = tid; i < D * D; i += 256) sW[i] = Wm[i];
    const float* xb = x + base * D;
    for (int i = tid; i < 64 * D; i += 256) sx[i] = xb[i];
    if (tid < 64) {
        const long n = base + tid;
        const unsigned a = agg[n];
        const int cnt = a & 0xFFFu, sc = (a >> 12) & 0x3FFu, dc = a >> 22;
        const int mix  = dc ? 0 : (sc ? atom_types[n] + 1 : 0);
        sstart[tid] = ((cnt > DEG_THRESH ? 3 : 0) + mix) * WINDOW;
    }
    __syncthreads();
    const float scale = 0.18257418583505536f;
    float* ob = out + base * D;
    for (int i = tid; i < 64 * D; i += 256) {
        const int nd = i / D, c = i - nd * D;
        float v = 0.0f;
        if ((unsigned)(c - sstart[nd]) < WINDOW) {
            float acc = 0.0f;
#pragma unroll
            for (int k = 0; k < D; ++k) acc += sx[nd * D + k] * sW[k * D + c];
            v = acc * scale;
        }
        ob[i] = v;
    }
}

// ---------------------------------------------------------------------------
extern "C" void kernel_launch(void* const* d_in, const int* in_sizes, int n_in,
                              void* d_out, int out_size, void* d_ws, size_t ws_size,
                              hipStream_t stream)
{
    const float* x          = (const float*)d_in[0];
    const float* Wm         = (const float*)d_in[1];
    const int*   edge_index = (const int*)d_in[2];
    const int*   atom_types = (const int*)d_in[3];
    float* out = (float*)d_out;

    if (ws_size >= WS_NEEDED && (size_t)out_size * 4 >= OUT_BYTES_NEEDED) {
        char* ws = (char*)d_ws;
        unsigned*       bm       = (unsigned*)(ws + WS_BM_OFF);
        unsigned*       cursors  = (unsigned*)(ws + WS_CUR_OFF);
        unsigned short* starts16 = (unsigned short*)(ws + WS_STARTS_OFF);
        unsigned*       partials = (unsigned*)(ws + WS_PART_OFF);
        unsigned short* buckets  = (unsigned short*)d_out;   // scratch, overwritten by out_pass

        pack_types<<<(N_NODES + 255) / 256, 256, 0, stream>>>(atom_types, bm, cursors);
        bin_edges<<<BIN_BLOCKS, BIN_THREADS, 0, stream>>>(edge_index, bm, buckets, cursors);
        hist_pass<<<P_PARTS * SLICES, 512, 0, stream>>>(buckets, cursors, partials);
        reduce_crit<<<(N_NODES / 2 + 255) / 256, 256, 0, stream>>>(partials, bm, starts16);
        out_pass<<<(N_NODES + ONPB - 1) / ONPB, 256, 0, stream>>>(
            x, Wm, (const unsigned char*)starts16, out);
    } else {
        unsigned* agg = (unsigned*)d_ws;
        hipMemsetAsync(agg, 0x00, N_NODES * sizeof(unsigned), stream);
        edge_pass_atomic<<<(N_EDGES / 4) / 256, 256, 0, stream>>>(edge_index, atom_types, agg);
        out_pass_agg<<<N_NODES / 64, 256, 0, stream>>>(x, Wm, agg, atom_types, out);
    }
}

// Round 5
// 421.875 us; speedup vs baseline: 3.7506x; 1.1449x over previous
//
#include <hip/hip_runtime.h>

// Problem constants (match reference)
#define N_NODES    1000000
#define N_EDGES    16000000
#define D          30
#define WINDOW     5
#define DEG_THRESH 10

// ---- binning params ----
#define P_PARTS    31                 // partitions of 32768 nodes
#define PART_BITS  15
#define PART_SIZE  32768
#define CAP        1081344            // records/bucket: mean 1.0486M + ~32 sigma
#define BUF_CAP    512                // LDS staging entries per bucket
#define BIN_BLOCKS 256
#define BIN_THREADS 1024
#define BIN_ITERS  16                 // 256*1024*16 = 4,194,304 groups >= 4M
#define N_GROUPS   (N_EDGES / 4)      // 4,000,000 int4-groups
#define BM_WORDS   (N_NODES / 32)     // 31250 u32 = 125000 B

// dynamic LDS layout for bin_edges
#define L_BM_BYTES   125000
#define L_BUF_BYTES  (P_PARTS * BUF_CAP * 2)   // 31744
#define L_CNT_OFF    (L_BM_BYTES + L_BUF_BYTES)
#define L_TOTAL      (L_CNT_OFF + P_PARTS * 4 * 3)   // 157,488 B <= 160 KiB

// ---- phase 2 ----
#define SLICES     8
#define HIST_WORDS 16384              // 32768 nodes, u32 per 2 nodes (c0:u8|c1:u8)

// ---- ws layout (bytes) ----
#define WS_BM_OFF      0              // u32 bitmask (131072 B reserved)
#define WS_CUR_OFF     131072         // u32[64] bucket cursors
#define WS_PART_OFF    131328         // u32[248 * 16384] slice partials (15.5 MiB)
#define WS_NEEDED      (WS_PART_OFF + (size_t)P_PARTS * SLICES * HIST_WORDS * 4)
#define OUT_BYTES_NEEDED ((size_t)P_PARTS * CAP * 2)   // 67 MB of d_out as scratch

// ---------------------------------------------------------------------------
// Phase 0: pack atom_types into a 1-bit-per-node bitmask; zero bucket cursors.
// ---------------------------------------------------------------------------
__global__ __launch_bounds__(256) void pack_types(
    const int* __restrict__ types,
    unsigned*  __restrict__ bm,
    unsigned*  __restrict__ cursors)
{
    const int g = blockIdx.x * 256 + threadIdx.x;
    const int v = (g < N_NODES) ? types[g] : 0;
    const unsigned long long m = __ballot(v);
    if ((threadIdx.x & 31) == 0 && g < N_NODES)
        bm[g >> 5] = (unsigned)(m >> (threadIdx.x & 32));
    if (blockIdx.x == 0 && threadIdx.x < 64) cursors[threadIdx.x] = 0u;
}

// ---------------------------------------------------------------------------
// Phase 1: single pass over edges -> binned u16 records (local_id<<1 | ntype).
// Type bitmask lives in LDS (125 KB) -> no global gathers at all. Records
// staged in LDS buckets, flushed coalesced; one cursor atomic per flush.
// ---------------------------------------------------------------------------
__global__ __launch_bounds__(BIN_THREADS, 1) void bin_edges(
    const int*      __restrict__ edge_index,   // [2, N_EDGES] int32
    const unsigned* __restrict__ bm,           // type bitmask (global)
    unsigned short* __restrict__ buckets,      // [P_PARTS][CAP] (in d_out scratch)
    unsigned*       __restrict__ cursors)      // [P_PARTS]
{
    extern __shared__ char smem[];
    unsigned* bm_lds = (unsigned*)smem;                               // 125000 B
    unsigned short (*buf)[BUF_CAP] =
        (unsigned short(*)[BUF_CAP])(smem + L_BM_BYTES);              // 31744 B
    unsigned* cnt   = (unsigned*)(smem + L_CNT_OFF);                  // [31]
    unsigned* basev = cnt + P_PARTS;
    unsigned* ccnt  = basev + P_PARTS;

    const int tid = threadIdx.x;
    for (int i = tid; i < BM_WORDS; i += BIN_THREADS) bm_lds[i] = bm[i];
    if (tid < P_PARTS) cnt[tid] = 0u;
    __syncthreads();

    for (int it = 0; it < BIN_ITERS; ++it) {
        const int g = (blockIdx.x * BIN_ITERS + it) * BIN_THREADS + tid;
        if (g < N_GROUPS) {
            const int e0 = g * 4;
            const int4 s4 = *reinterpret_cast<const int4*>(edge_index + e0);
            const int4 d4 = *reinterpret_cast<const int4*>(edge_index + N_EDGES + e0);
            const int ss[4] = {s4.x, s4.y, s4.z, s4.w};
            const int dd[4] = {d4.x, d4.y, d4.z, d4.w};
#pragma unroll
            for (int k = 0; k < 4; ++k) {
                const int s = ss[k], d = dd[k];
                const unsigned ts = (bm_lds[(unsigned)s >> 5] >> (s & 31)) & 1u;
                const unsigned td = (bm_lds[(unsigned)d >> 5] >> (d & 31)) & 1u;
                {   // record for endpoint s carries d's type
                    const int b = s >> PART_BITS;
                    const unsigned short rec =
                        (unsigned short)(((s & (PART_SIZE - 1)) << 1) | td);
                    const unsigned pos = atomicAdd(&cnt[b], 1u);
                    if (pos < BUF_CAP) buf[b][pos] = rec;
                    else {  // statistically ~never: direct spill
                        const unsigned gp = atomicAdd(&cursors[b], 1u);
                        if (gp < CAP) buckets[(size_t)b * CAP + gp] = rec;
                    }
                }
                {   // record for endpoint d carries s's type
                    const int b = d >> PART_BITS;
                    const unsigned short rec =
                        (unsigned short)(((d & (PART_SIZE - 1)) << 1) | ts);
                    const unsigned pos = atomicAdd(&cnt[b], 1u);
                    if (pos < BUF_CAP) buf[b][pos] = rec;
                    else {
                        const unsigned gp = atomicAdd(&cursors[b], 1u);
                        if (gp < CAP) buckets[(size_t)b * CAP + gp] = rec;
                    }
                }
            }
        }
        __syncthreads();
        if (tid < P_PARTS) {
            unsigned c = cnt[tid]; if (c > BUF_CAP) c = BUF_CAP;
            unsigned bse = 0u;
            if (c) {
                bse = atomicAdd(&cursors[tid], c);
                if (bse > CAP) bse = CAP;
                if (bse + c > CAP) c = CAP - bse;   // memory-safety clamp
            }
            ccnt[tid] = c; basev[tid] = bse; cnt[tid] = 0u;
        }
        __syncthreads();
        // coalesced flush: wave w copies buckets 2w, 2w+1
        const int w = tid >> 6, lane = tid & 63;
#pragma unroll
        for (int j = 0; j < 2; ++j) {
            const int b = w * 2 + j;
            if (b < P_PARTS) {
                const unsigned c = ccnt[b];
                unsigned short* dst = buckets + (size_t)b * CAP + basev[b];
                for (unsigned e = lane; e < c; e += 64) dst[e] = buf[b][e];
            }
        }
        __syncthreads();
    }
}

// ---------------------------------------------------------------------------
// Phase 2: per (partition, slice) block builds a 64 KB LDS histogram
// (c0:u8 | c1:u8 per node, 2 nodes per u32) from its record slice.
// ---------------------------------------------------------------------------
__global__ __launch_bounds__(512) void hist_pass(
    const unsigned short* __restrict__ buckets,
    const unsigned*       __restrict__ cursors,
    unsigned*             __restrict__ partials)   // [P*SLICES][HIST_WORDS]
{
    __shared__ unsigned hist[HIST_WORDS];          // exactly 64 KiB
    const int p = blockIdx.x >> 3, s = blockIdx.x & 7;
    const int tid = threadIdx.x;
    for (int i = tid; i < HIST_WORDS; i += 512) hist[i] = 0u;
    __syncthreads();

    unsigned count = cursors[p]; if (count > CAP) count = CAP;
    const unsigned short* bk = buckets + (size_t)p * CAP;
    const unsigned n4 = (count + 3u) >> 2;
    for (unsigned j = (unsigned)(s * 512 + tid); j < n4; j += SLICES * 512) {
        const unsigned i0 = j * 4u;
        if (i0 + 4u <= count) {
            const ushort4 r4 = *reinterpret_cast<const ushort4*>(bk + i0);
            const unsigned short rr[4] = {r4.x, r4.y, r4.z, r4.w};
#pragma unroll
            for (int k = 0; k < 4; ++k) {
                const unsigned rec = rr[k];
                const unsigned local = rec >> 1, t = rec & 1u;
                atomicAdd(&hist[local >> 1], (1u << (8u * t)) << (16u * (local & 1u)));
            }
        } else {
            for (unsigned i = i0; i < count; ++i) {
                const unsigned rec = bk[i];
                const unsigned local = rec >> 1, t = rec & 1u;
                atomicAdd(&hist[local >> 1], (1u << (8u * t)) << (16u * (local & 1u)));
            }
        }
    }
    __syncthreads();
    unsigned* op = partials + (size_t)blockIdx.x * HIST_WORDS;
    for (int i = tid; i < HIST_WORDS; i += 512) op[i] = hist[i];
}

// ---------------------------------------------------------------------------
// Phase 3 (fused reduce + output): 256 nodes/block (always within ONE
// partition since 32768 % 256 == 0). 128 threads SWAR-reduce the 8 slice
// partials -> per-node window start in LDS; then x row in registers, 5 dots
// vs LDS W, row assembled in LDS, fully coalesced global in/out.
// ---------------------------------------------------------------------------
#define ONPB 256
__global__ __launch_bounds__(256) void out_pass(
    const float* __restrict__ x, const float* __restrict__ Wm,
    const unsigned* __restrict__ partials,
    const unsigned* __restrict__ bm,
    float* __restrict__ out)
{
    __shared__ float sx[ONPB * 31];     // padded rows (stride 31)
    __shared__ float sW[D * D];
    __shared__ unsigned char sst[ONPB];
    const int tid   = threadIdx.x;
    const long base = (long)blockIdx.x * ONPB;
    const long tot  = (long)N_NODES * D;

    for (int i = tid; i < D * D; i += 256) sW[i] = Wm[i];
    for (int i = tid; i < ONPB * D; i += 256) {
        const int n = i / D, c = i - n * D;
        const long gi = base * D + i;
        sx[n * 31 + c] = (gi < tot) ? x[gi] : 0.0f;
    }
    if (tid < ONPB / 2) {
        const unsigned Wd = (unsigned)(base >> 1) + tid;   // word = 2 nodes
        unsigned st0 = 0, st1 = 0;
        if (Wd < N_NODES / 2) {
            const unsigned p = Wd >> 14, widx = Wd & 16383u;
            const unsigned* pp = partials + (size_t)(p * SLICES) * HIST_WORDS + widx;
            unsigned sum = 0u;
#pragma unroll
            for (int s = 0; s < SLICES; ++s) sum += pp[(size_t)s * HIST_WORDS];
            const unsigned bmw = bm[Wd >> 4];
            unsigned st[2];
#pragma unroll
            for (int h = 0; h < 2; ++h) {
                const unsigned c0 = (sum >> (16 * h)) & 0xFFu;
                const unsigned c1 = (sum >> (16 * h + 8)) & 0xFFu;
                const unsigned t  = (bmw >> ((Wd & 15u) * 2u + (unsigned)h)) & 1u;
                const unsigned cnt    = c0 + c1;
                const unsigned same_c = t ? c1 : c0;
                const unsigned diff_c = t ? c0 : c1;
                const int mix  = diff_c ? 0 : (same_c ? (int)t + 1 : 0);
                const int crit = (cnt > DEG_THRESH ? 3 : 0) + mix;
                st[h] = (unsigned)(crit * WINDOW);
            }
            st0 = st[0]; st1 = st[1];
        }
        sst[2 * tid]     = (unsigned char)st0;
        sst[2 * tid + 1] = (unsigned char)st1;
    }
    __syncthreads();

    float xr[D];
#pragma unroll
    for (int k = 0; k < D; ++k) xr[k] = sx[tid * 31 + k];
    const int start = sst[tid];
    float acc[WINDOW];
#pragma unroll
    for (int cc = 0; cc < WINDOW; ++cc) {
        const int col = start + cc;
        float a = 0.0f;
#pragma unroll
        for (int k = 0; k < D; ++k) a += xr[k] * sW[k * D + col];
        acc[cc] = a * 0.18257418583505536f;   // 1/sqrt(30)
    }
    __syncthreads();                          // everyone done reading sx
#pragma unroll
    for (int k = 0; k < D; ++k) sx[tid * 31 + k] = 0.0f;
#pragma unroll
    for (int cc = 0; cc < WINDOW; ++cc) sx[tid * 31 + start + cc] = acc[cc];
    __syncthreads();
    for (int i = tid; i < ONPB * D; i += 256) {
        const int n = i / D, c = i - n * D;
        const long gi = base * D + i;
        if (gi < tot) out[gi] = sx[n * 31 + c];
    }
}

// ===========================================================================
// Fallback (round-2 atomic path) if buffers are unexpectedly small.
// ===========================================================================
#define SAME_INC (1u << 12)
#define DIFF_INC (1u << 22)

__global__ __launch_bounds__(256) void edge_pass_atomic(
    const int* __restrict__ edge_index, const int* __restrict__ atom_types,
    unsigned* __restrict__ agg)
{
    const int t  = blockIdx.x * blockDim.x + threadIdx.x;
    const int e0 = t * 4;
    if (e0 >= N_EDGES) return;
    const int4 s4 = *reinterpret_cast<const int4*>(edge_index + e0);
    const int4 d4 = *reinterpret_cast<const int4*>(edge_index + N_EDGES + e0);
    const int ss[4] = {s4.x, s4.y, s4.z, s4.w};
    const int dd[4] = {d4.x, d4.y, d4.z, d4.w};
#pragma unroll
    for (int k = 0; k < 4; ++k) {
        const int s = ss[k], d = dd[k];
        const unsigned add = 1u + ((atom_types[s] == atom_types[d]) ? SAME_INC : DIFF_INC);
        atomicAdd(agg + s, add);
        atomicAdd(agg + d, add);
    }
}

__global__ __launch_bounds__(256) void out_pass_agg(
    const float* __restrict__ x, const float* __restrict__ Wm,
    const unsigned* __restrict__ agg, const int* __restrict__ atom_types,
    float* __restrict__ out)
{
    __shared__ float sx[64 * D];
    __shared__ float sW[D * D];
    __shared__ int   sstart[64];
    const int tid   = threadIdx.x;
    const long base = (long)blockIdx.x * 64;
    for (int i = tid; i < D * D; i += 256) sW[i] = Wm[i];
    const float* xb = x + base * D;
    for (int i = tid; i < 64 * D; i += 256) sx[i] = xb[i];
    if (tid < 64) {
        const long n = base + tid;
        const unsigned a = agg[n];
        const int cnt = a & 0xFFFu, sc = (a >> 12) & 0x3FFu, dc = a >> 22;
        const int mix  = dc ? 0 : (sc ? atom_types[n] + 1 : 0);
        sstart[tid] = ((cnt > DEG_THRESH ? 3 : 0) + mix) * WINDOW;
    }
    __syncthreads();
    const float scale = 0.18257418583505536f;
    float* ob = out + base * D;
    for (int i = tid; i < 64 * D; i += 256) {
        const int nd = i / D, c = i - nd * D;
        float v = 0.0f;
        if ((unsigned)(c - sstart[nd]) < WINDOW) {
            float acc = 0.0f;
#pragma unroll
            for (int k = 0; k < D; ++k) acc += sx[nd * D + k] * sW[k * D + c];
            v = acc * scale;
        }
        ob[i] = v;
    }
}

// ---------------------------------------------------------------------------
extern "C" void kernel_launch(void* const* d_in, const int* in_sizes, int n_in,
                              void* d_out, int out_size, void* d_ws, size_t ws_size,
                              hipStream_t stream)
{
    const float* x          = (const float*)d_in[0];
    const float* Wm         = (const float*)d_in[1];
    const int*   edge_index = (const int*)d_in[2];
    const int*   atom_types = (const int*)d_in[3];
    float* out = (float*)d_out;

    if (ws_size >= WS_NEEDED && (size_t)out_size * 4 >= OUT_BYTES_NEEDED) {
        char* ws = (char*)d_ws;
        unsigned*       bm       = (unsigned*)(ws + WS_BM_OFF);
        unsigned*       cursors  = (unsigned*)(ws + WS_CUR_OFF);
        unsigned*       partials = (unsigned*)(ws + WS_PART_OFF);
        unsigned short* buckets  = (unsigned short*)d_out;   // scratch, overwritten

        pack_types<<<(N_NODES + 255) / 256, 256, 0, stream>>>(atom_types, bm, cursors);
        bin_edges<<<BIN_BLOCKS, BIN_THREADS, L_TOTAL, stream>>>(edge_index, bm,
                                                                buckets, cursors);
        hist_pass<<<P_PARTS * SLICES, 512, 0, stream>>>(buckets, cursors, partials);
        out_pass<<<(N_NODES + ONPB - 1) / ONPB, 256, 0, stream>>>(
            x, Wm, partials, bm, out);
    } else {
        unsigned* agg = (unsigned*)d_ws;
        hipMemsetAsync(agg, 0x00, N_NODES * sizeof(unsigned), stream);
        edge_pass_atomic<<<(N_EDGES / 4) / 256, 256, 0, stream>>>(edge_index, atom_types, agg);
        out_pass_agg<<<N_NODES / 64, 256, 0, stream>>>(x, Wm, agg, atom_types, out);
    }
}